// Round 7
// baseline (1179.094 us; speedup 1.0000x reference)
//
#include <hip/hip_runtime.h>
#include <math.h>

// Problem constants
#define NSEQ 4
#define BATCH 256
#define T 64
#define FIN 32
#define S 512
#define KTOT 544     // FIN + S unified k-dimension

// Pipelined decomposition: 4 lanes concurrent (lane i lags i-1 by 1 step).
// Per lane: 16 groups x 16 rows, 8 slice-WGs x 64 cols. 4*16*8 = 512 WGs.
// NT=512 (8 waves); 2 WGs/CU (LDS 73KB x2 <= 160KB) -> 4 waves/SIMD exactly.
#define NT 512
#define NWG 512
#define RPG 16
#define SW 64
#define DEPTH 4
#define KPW 68       // k per wave (544/8)

// ws float offsets
#define RING_SZ  (4ull * DEPTH * BATCH * S)        // 8 MB state ring
#define OUTP_OFF RING_SZ                            // [gid][sl][16] partials
#define CTL_OFF  (RING_SZ + 16384ull)               // counters: gid*32 uints

#define FLAG_MAGIC 0x13572468u

#define HS2 548   // h_lds row stride: [x(32)|hc(512)] + pad4 (16B-aligned rows)
#define RS2 66    // red row stride (64+2)

// ---- U weights: 68 named scalars, allocator budget forced to 128 ----------
// R5/R6 post-mortem: with __launch_bounds__(512,4) the allocator hard-targets
// 64 VGPRs (8 waves/EU) and spills U to scratch -> 2.7 GB/launch HBM churn
// (WRITE_SIZE showed ~18 spill-stores/thread/STEP). But LDS (73 KB -> 2 WG/CU)
// caps occupancy at 4 waves/SIMD anyway — the spill buys nothing.
// amdgpu_waves_per_eu(4,4) pins min=max=4 -> full 128-VGPR budget, no
// incentive to shrink. PIN_U makes each loaded value opaque (no remat).
#define REP68(M) \
  M(0) M(1) M(2) M(3) M(4) M(5) M(6) M(7) M(8) M(9) \
  M(10) M(11) M(12) M(13) M(14) M(15) M(16) M(17) M(18) M(19) \
  M(20) M(21) M(22) M(23) M(24) M(25) M(26) M(27) M(28) M(29) \
  M(30) M(31) M(32) M(33) M(34) M(35) M(36) M(37) M(38) M(39) \
  M(40) M(41) M(42) M(43) M(44) M(45) M(46) M(47) M(48) M(49) \
  M(50) M(51) M(52) M(53) M(54) M(55) M(56) M(57) M(58) M(59) \
  M(60) M(61) M(62) M(63) M(64) M(65) M(66) M(67)

#define DECL_U(i) float U##i;
#define LOAD_U(i) U##i = Wc[(size_t)(kc * KPW + (i)) * S + sb + col];
#define PIN_U(i)  asm("" : "+v"(U##i));

#define MV4(u, A, B, C, D) { \
  const float4 h4 = *(const float4*)(hrow + (u) * 4); \
  a0 = fmaf(h4.x, A, a0); a1 = fmaf(h4.y, B, a1); \
  a2 = fmaf(h4.z, C, a2); a3 = fmaf(h4.w, D, a3); }

#define MV_ALL \
  MV4(0,  U0,  U1,  U2,  U3)  MV4(1,  U4,  U5,  U6,  U7) \
  MV4(2,  U8,  U9,  U10, U11) MV4(3,  U12, U13, U14, U15) \
  MV4(4,  U16, U17, U18, U19) MV4(5,  U20, U21, U22, U23) \
  MV4(6,  U24, U25, U26, U27) MV4(7,  U28, U29, U30, U31) \
  MV4(8,  U32, U33, U34, U35) MV4(9,  U36, U37, U38, U39) \
  MV4(10, U40, U41, U42, U43) MV4(11, U44, U45, U46, U47) \
  MV4(12, U48, U49, U50, U51) MV4(13, U52, U53, U54, U55) \
  MV4(14, U56, U57, U58, U59) MV4(15, U60, U61, U62, U63) \
  MV4(16, U64, U65, U66, U67)

__device__ __forceinline__ unsigned ld_cnt(const unsigned* p) {
  return __hip_atomic_load(p, __ATOMIC_RELAXED, __HIP_MEMORY_SCOPE_AGENT);
}

// ---- coherent (MALL) ring I/O via sc0 sc1 asm (R4-proven) -----------------
__device__ __forceinline__ void cstore1(float* p, float v) {
  asm volatile("global_store_dword %0, %1, off sc0 sc1" :: "v"(p), "v"(v) : "memory");
}
__device__ __forceinline__ float cload1(const float* p) {
  float v;
  asm volatile("global_load_dword %0, %1, off sc0 sc1\n\ts_waitcnt vmcnt(0)"
               : "=v"(v) : "v"(p) : "memory");
  return v;
}
__device__ __forceinline__ void cload_row(float4* d, const float* p) {
  asm volatile(
      "global_load_dwordx4 %0, %4, off sc0 sc1\n\t"
      "global_load_dwordx4 %1, %4, off offset:512 sc0 sc1\n\t"
      "global_load_dwordx4 %2, %4, off offset:1024 sc0 sc1\n\t"
      "global_load_dwordx4 %3, %4, off offset:1536 sc0 sc1\n\t"
      "s_waitcnt vmcnt(0)"
      : "=&v"(d[0]), "=&v"(d[1]), "=&v"(d[2]), "=&v"(d[3])
      : "v"(p) : "memory");
}
__device__ __forceinline__ void cload_row2(float4* h, float4* q,
                                           const float* ph, const float* pp) {
  asm volatile(
      "global_load_dwordx4 %0, %8, off sc0 sc1\n\t"
      "global_load_dwordx4 %1, %8, off offset:512 sc0 sc1\n\t"
      "global_load_dwordx4 %2, %8, off offset:1024 sc0 sc1\n\t"
      "global_load_dwordx4 %3, %8, off offset:1536 sc0 sc1\n\t"
      "global_load_dwordx4 %4, %9, off sc0 sc1\n\t"
      "global_load_dwordx4 %5, %9, off offset:512 sc0 sc1\n\t"
      "global_load_dwordx4 %6, %9, off offset:1024 sc0 sc1\n\t"
      "global_load_dwordx4 %7, %9, off offset:1536 sc0 sc1\n\t"
      "s_waitcnt vmcnt(0)"
      : "=&v"(h[0]), "=&v"(h[1]), "=&v"(h[2]), "=&v"(h[3]),
        "=&v"(q[0]), "=&v"(q[1]), "=&v"(q[2]), "=&v"(q[3])
      : "v"(ph), "v"(pp) : "memory");
}

extern "C" __global__ void __launch_bounds__(NT)
__attribute__((amdgpu_waves_per_eu(4, 4)))
rnn_pipe4(const float* __restrict__ x,      // [4][256][64][32]
          const float* __restrict__ Wcell,  // [4][544][512]
          const float* __restrict__ bcell,  // [4][512]
          const float* __restrict__ Wcomb,  // [3][1024]
          const float* __restrict__ bcomb,  // [3]
          const float* __restrict__ Wout,   // [512]
          float* __restrict__ out,          // [1024] = [lane][batch]
          float* __restrict__ ws)
{
  const int b    = blockIdx.x;
  const int sl   = b & 7;          // slice (round-robins XCDs)
  const int gid  = b >> 3;         // 0..63 = lane*16 + grp
  const int lane = gid >> 4;
  const int grp  = gid & 15;
  const int r0 = grp * RPG, sb = sl * SW;
  const int tid = threadIdx.x;

  __shared__ __align__(16) float h_lds[RPG * HS2];   // 35.1 KB [x|hc] rows
  __shared__ __align__(16) float red[8 * RPG * RS2]; // 33.8 KB [kc][r][col]
  __shared__ float wg_lds[2 * S];                    //  4.0 KB gate weights
  __shared__ float obuf[16];

  float* ring = ws;
  unsigned* ctl      = (unsigned*)(ws + CTL_OFF);
  unsigned* cnt_own  = ctl + gid * 32;
  unsigned* flg_own  = cnt_own + 16;
  unsigned* cnt_prod = ctl + (gid - 16) * 32;  // valid iff lane>0
  unsigned* cnt_cons = ctl + (gid + 16) * 32;  // valid iff lane<3

  // ---- init handshake (poison-keyed flag) ----
  if (sl == 0 && tid == 0) {
    __hip_atomic_store(cnt_own, 0u, __ATOMIC_RELAXED, __HIP_MEMORY_SCOPE_AGENT);
    __hip_atomic_store(flg_own, FLAG_MAGIC, __ATOMIC_RELEASE, __HIP_MEMORY_SCOPE_AGENT);
  }
  if (tid == 0) {
    while (__hip_atomic_load(flg_own, __ATOMIC_ACQUIRE, __HIP_MEMORY_SCOPE_AGENT) != FLAG_MAGIC)
      __builtin_amdgcn_s_sleep(1);
    if (lane > 0)
      while (__hip_atomic_load(cnt_prod + 16, __ATOMIC_ACQUIRE, __HIP_MEMORY_SCOPE_AGENT) != FLAG_MAGIC)
        __builtin_amdgcn_s_sleep(1);
    if (lane < 3)
      while (__hip_atomic_load(cnt_cons + 16, __ATOMIC_ACQUIRE, __HIP_MEMORY_SCOPE_AGENT) != FLAG_MAGIC)
        __builtin_amdgcn_s_sleep(1);
  }

  // ---- per-thread constants ----
  const float* Wc = Wcell + (size_t)lane * KTOT * S;
  const int kc  = tid >> 6;        // wave = k-chunk [kc*68, kc*68+68)
  const int col = tid & 63;        // this thread's s-column within slice
  REP68(DECL_U)
  REP68(LOAD_U)
  REP68(PIN_U)
  const float bcv = bcell[lane * S + sb + col];
  const float wov = Wout[sb + col];
  for (int idx = tid; idx < 2 * S; idx += NT)
    wg_lds[idx] = (lane > 0) ? Wcomb[(size_t)(lane - 1) * 2 * S + idx] : 0.0f;
  const float bg = (lane > 0) ? bcomb[lane - 1] : 0.0f;
  // stage/gate mapping: 32 threads per row
  const int grow = tid >> 5, gch = tid & 31;
  // reduce mapping: rows {rb, rb+8}
  const int rb = tid >> 6;
  __syncthreads();

  float oacc0 = 0.f, oacc1 = 0.f;

  for (int t = 0; t < T; ++t) {
    // ---- phase A: x stage + split-phase polls ----
    h_lds[grow * HS2 + gch] =
        x[(((size_t)lane * BATCH + r0 + grow) * T + t) * FIN + gch];
    if (tid == 0) {
      if (t > 0)                  while (ld_cnt(cnt_own)  < 8u * (unsigned)t) {}
      if (lane > 0)               while (ld_cnt(cnt_prod) < 8u * (unsigned)(t + 1)) {}
      if (lane < 3 && t >= DEPTH) while (ld_cnt(cnt_cons) < 8u * (unsigned)(t - 3)) {}
    }
    __syncthreads();

    // ---- phase B: coherent ring loads + wave-local gate + stage hc --------
    float4 hv[4], pv[4];
    const float* hb = ring + ((size_t)(lane * DEPTH + ((t - 1) & 3)) * BATCH + r0 + grow) * S + gch * 4;
    const float* pb = ring + ((size_t)((lane - 1) * DEPTH + (t & 3)) * BATCH + r0 + grow) * S + gch * 4;
    if (t > 0) {
      if (lane > 0) cload_row2(hv, pv, hb, pb);
      else          cload_row(hv, hb);
    } else {
      #pragma unroll
      for (int j = 0; j < 4; ++j) hv[j] = make_float4(0.f, 0.f, 0.f, 0.f);
      if (lane > 0) cload_row(pv, pb);
    }
    if (lane > 0) {
      float gs = 0.0f;
      #pragma unroll
      for (int j = 0; j < 4; ++j) {
        const float* wh = &wg_lds[j * 128 + gch * 4];
        const float* wp = wh + S;
        gs += hv[j].x * wh[0] + hv[j].y * wh[1] + hv[j].z * wh[2] + hv[j].w * wh[3];
        gs += pv[j].x * wp[0] + pv[j].y * wp[1] + pv[j].z * wp[2] + pv[j].w * wp[3];
      }
      gs += __shfl_xor(gs, 1);  gs += __shfl_xor(gs, 2);  gs += __shfl_xor(gs, 4);
      gs += __shfl_xor(gs, 8);  gs += __shfl_xor(gs, 16);  // 32-lane row halves
      const float w = 1.0f / (1.0f + __expf(-(gs + bg)));
      #pragma unroll
      for (int j = 0; j < 4; ++j) {  // hc = p + w*(h-p)
        hv[j].x = fmaf(w, hv[j].x - pv[j].x, pv[j].x);
        hv[j].y = fmaf(w, hv[j].y - pv[j].y, pv[j].y);
        hv[j].z = fmaf(w, hv[j].z - pv[j].z, pv[j].z);
        hv[j].w = fmaf(w, hv[j].w - pv[j].w, pv[j].w);
      }
    }
    #pragma unroll
    for (int j = 0; j < 4; ++j)
      *(float4*)&h_lds[grow * HS2 + 32 + j * 128 + gch * 4] = hv[j];
    __syncthreads();

    // ---- phase C: matvec over unified [x|hc] rows, all 16 rows, 1 pass ----
    #pragma unroll
    for (int r = 0; r < RPG; ++r) {
      const float* hrow = &h_lds[r * HS2 + kc * KPW];  // 272B-aligned
      float a0 = 0.f, a1 = 0.f, a2 = 0.f, a3 = 0.f;
      MV_ALL
      red[(kc * RPG + r) * RS2 + col] = (a0 + a1) + (a2 + a3);
    }
    __syncthreads();

    // ---- phase D: reduce 8 kc + tanh + coherent store ---------------------
    float* slot = ring + ((size_t)(lane * DEPTH + (t & 3)) * BATCH + r0) * S + sb;
    #pragma unroll
    for (int j = 0; j < 2; ++j) {
      const int r = rb + 8 * j;
      float s2 = bcv;
      #pragma unroll
      for (int c = 0; c < 8; ++c) s2 += red[(c * RPG + r) * RS2 + col];
      const float aa = fabsf(s2), ee = __expf(2.0f * aa);
      const float th = copysignf(1.0f - 2.0f / (ee + 1.0f), s2);
      cstore1(slot + (size_t)r * S + col, th);
      if (t == T - 1) { if (j == 0) oacc0 = th * wov; else oacc1 = th * wov; }
    }
    __syncthreads();  // drains vmcnt -> cstores at MALL before arrive
    if (tid == 0)
      __hip_atomic_fetch_add(cnt_own, 1u, __ATOMIC_RELAXED, __HIP_MEMORY_SCOPE_AGENT);
  }

  // ---- output: out[lane*256 + r] = h_T[r] . Wout --------------------------
  {
    float v0 = oacc0, v1 = oacc1;
    #pragma unroll
    for (int m = 1; m < 64; m <<= 1) { v0 += __shfl_xor(v0, m); v1 += __shfl_xor(v1, m); }
    if ((tid & 63) == 0) { obuf[rb] = v0; obuf[rb + 8] = v1; }  // rows {rb, rb+8}
  }
  __syncthreads();
  if (tid < 16)
    cstore1(ws + OUTP_OFF + (size_t)((gid * 8 + sl) * 16 + tid), obuf[tid]);
  __syncthreads();
  if (tid == 0)
    __hip_atomic_fetch_add(cnt_own, 1u, __ATOMIC_RELAXED, __HIP_MEMORY_SCOPE_AGENT);
  if (sl == 0) {
    if (tid == 0)
      while (ld_cnt(cnt_own) < 8u * (unsigned)(T + 1)) {}
    __syncthreads();
    if (tid < 128) {
      const int sli = tid >> 4, r = tid & 15;
      red[tid] = cload1(ws + OUTP_OFF + (size_t)((gid * 8 + sli) * 16 + r));
    }
    __syncthreads();
    if (tid < 16) {
      float s2 = 0.f;
      #pragma unroll
      for (int sli = 0; sli < 8; ++sli) s2 += red[sli * 16 + tid];
      out[lane * BATCH + r0 + tid] = s2;
    }
  }
}

extern "C" void kernel_launch(void* const* d_in, const int* in_sizes, int n_in,
                              void* d_out, int out_size, void* d_ws, size_t ws_size,
                              hipStream_t stream) {
  (void)in_sizes; (void)n_in; (void)out_size; (void)ws_size;
  rnn_pipe4<<<dim3(NWG), dim3(NT), 0, stream>>>(
      (const float*)d_in[0],   // inputs
      (const float*)d_in[1],   // W_cell
      (const float*)d_in[2],   // b_cell
      (const float*)d_in[3],   // W_comb
      (const float*)d_in[4],   // b_comb
      (const float*)d_in[5],   // W_out
      (float*)d_out,
      (float*)d_ws);
}

// Round 8
// 761.758 us; speedup vs baseline: 1.5479x; 1.5479x over previous
//
#include <hip/hip_runtime.h>
#include <math.h>

// Problem constants
#define NSEQ 4
#define BATCH 256
#define T 64
#define FIN 32
#define S 512
#define KTOT 544     // FIN + S unified k-dimension

// Pipelined decomposition: 4 lanes concurrent (lane i lags i-1 by 1 step).
// Per lane: 16 groups x 16 rows, 8 slice-WGs x 64 cols. 4*16*8 = 512 WGs.
// NT=256 (4 waves); 2 WGs/CU (LDS 73KB x2 <= 160KB, VGPR ~190 <= 256).
// launch_bounds(256,1): the ONLY config where the allocator promoted a large
// weight array to VGPRs (R2: float2 U[64] -> VGPR_Count=148, no scratch).
// NT=512 variants all hard-spilled to 64 VGPRs regardless of attributes.
#define NT 256
#define NWG 512
#define RPG 16
#define SW 64
#define DEPTH 4
#define KPW 68       // k per chunk (544/8)

// ws float offsets
#define RING_SZ  (4ull * DEPTH * BATCH * S)        // 8 MB state ring
#define OUTP_OFF RING_SZ                            // [gid][sl][16] partials
#define CTL_OFF  (RING_SZ + 16384ull)               // counters: gid*32 uints

#define FLAG_MAGIC 0x13572468u

#define HS2 548   // h_lds row stride: [x(32)|hc(512)] + pad4 (16B-aligned rows)
#define RS2 66    // red row stride (64+2)

__device__ __forceinline__ unsigned ld_cnt(const unsigned* p) {
  return __hip_atomic_load(p, __ATOMIC_RELAXED, __HIP_MEMORY_SCOPE_AGENT);
}

// ---- coherent (MALL) ring I/O via sc0 sc1 asm (R4-proven) -----------------
__device__ __forceinline__ void cstore1(float* p, float v) {
  asm volatile("global_store_dword %0, %1, off sc0 sc1" :: "v"(p), "v"(v) : "memory");
}
__device__ __forceinline__ float cload1(const float* p) {
  float v;
  asm volatile("global_load_dword %0, %1, off sc0 sc1\n\ts_waitcnt vmcnt(0)"
               : "=v"(v) : "v"(p) : "memory");
  return v;
}
__device__ __forceinline__ void cload_row(float4* d, const float* p) {
  asm volatile(
      "global_load_dwordx4 %0, %4, off sc0 sc1\n\t"
      "global_load_dwordx4 %1, %4, off offset:512 sc0 sc1\n\t"
      "global_load_dwordx4 %2, %4, off offset:1024 sc0 sc1\n\t"
      "global_load_dwordx4 %3, %4, off offset:1536 sc0 sc1\n\t"
      "s_waitcnt vmcnt(0)"
      : "=&v"(d[0]), "=&v"(d[1]), "=&v"(d[2]), "=&v"(d[3])
      : "v"(p) : "memory");
}
__device__ __forceinline__ void cload_row2(float4* h, float4* q,
                                           const float* ph, const float* pp) {
  asm volatile(
      "global_load_dwordx4 %0, %8, off sc0 sc1\n\t"
      "global_load_dwordx4 %1, %8, off offset:512 sc0 sc1\n\t"
      "global_load_dwordx4 %2, %8, off offset:1024 sc0 sc1\n\t"
      "global_load_dwordx4 %3, %8, off offset:1536 sc0 sc1\n\t"
      "global_load_dwordx4 %4, %9, off sc0 sc1\n\t"
      "global_load_dwordx4 %5, %9, off offset:512 sc0 sc1\n\t"
      "global_load_dwordx4 %6, %9, off offset:1024 sc0 sc1\n\t"
      "global_load_dwordx4 %7, %9, off offset:1536 sc0 sc1\n\t"
      "s_waitcnt vmcnt(0)"
      : "=&v"(h[0]), "=&v"(h[1]), "=&v"(h[2]), "=&v"(h[3]),
        "=&v"(q[0]), "=&v"(q[1]), "=&v"(q[2]), "=&v"(q[3])
      : "v"(ph), "v"(pp) : "memory");
}
__device__ __forceinline__ float2 fma2v(float s, float2 u, float2 a) {
  a.x = fmaf(s, u.x, a.x); a.y = fmaf(s, u.y, a.y); return a;
}

extern "C" __global__ void __launch_bounds__(NT, 1)
rnn_pipe5(const float* __restrict__ x,      // [4][256][64][32]
          const float* __restrict__ Wcell,  // [4][544][512]
          const float* __restrict__ bcell,  // [4][512]
          const float* __restrict__ Wcomb,  // [3][1024]
          const float* __restrict__ bcomb,  // [3]
          const float* __restrict__ Wout,   // [512]
          float* __restrict__ out,          // [1024] = [lane][batch]
          float* __restrict__ ws)
{
  const int b    = blockIdx.x;
  const int sl   = b & 7;          // slice (round-robins XCDs)
  const int gid  = b >> 3;         // 0..63 = lane*16 + grp
  const int lane = gid >> 4;
  const int grp  = gid & 15;
  const int r0 = grp * RPG, sb = sl * SW;
  const int tid = threadIdx.x;

  __shared__ __align__(16) float h_lds[RPG * HS2];   // 35.1 KB [x|hc] rows
  __shared__ __align__(16) float red[8 * RPG * RS2]; // 33.8 KB [kc][r][col]
  __shared__ float wg_lds[2 * S];                    //  4.0 KB gate weights
  __shared__ float obuf[16];

  float* ring = ws;
  unsigned* ctl      = (unsigned*)(ws + CTL_OFF);
  unsigned* cnt_own  = ctl + gid * 32;
  unsigned* flg_own  = cnt_own + 16;
  unsigned* cnt_prod = ctl + (gid - 16) * 32;  // valid iff lane>0
  unsigned* cnt_cons = ctl + (gid + 16) * 32;  // valid iff lane<3

  // ---- init handshake (poison-keyed flag) ----
  if (sl == 0 && tid == 0) {
    __hip_atomic_store(cnt_own, 0u, __ATOMIC_RELAXED, __HIP_MEMORY_SCOPE_AGENT);
    __hip_atomic_store(flg_own, FLAG_MAGIC, __ATOMIC_RELEASE, __HIP_MEMORY_SCOPE_AGENT);
  }
  if (tid == 0) {
    while (__hip_atomic_load(flg_own, __ATOMIC_ACQUIRE, __HIP_MEMORY_SCOPE_AGENT) != FLAG_MAGIC)
      __builtin_amdgcn_s_sleep(1);
    if (lane > 0)
      while (__hip_atomic_load(cnt_prod + 16, __ATOMIC_ACQUIRE, __HIP_MEMORY_SCOPE_AGENT) != FLAG_MAGIC)
        __builtin_amdgcn_s_sleep(1);
    if (lane < 3)
      while (__hip_atomic_load(cnt_cons + 16, __ATOMIC_ACQUIRE, __HIP_MEMORY_SCOPE_AGENT) != FLAG_MAGIC)
        __builtin_amdgcn_s_sleep(1);
  }

  // ---- per-thread constants ----
  const float* Wc = Wcell + (size_t)lane * KTOT * S;
  const int kc = tid >> 5;         // 0..7: k-chunk [kc*68, kc*68+68)
  const int cp = tid & 31;         // cols {2cp, 2cp+1} within slice
  // U slice: 68 float2 = 136 VGPRs. Constant-indexed array, (256,1) budget —
  // the R2-proven promote-alloca path. Each LDS h4 broadcast feeds 8 FMAs.
  float2 U2[KPW];
  #pragma unroll
  for (int k = 0; k < KPW; ++k)
    U2[k] = *(const float2*)(Wc + (size_t)(kc * KPW + k) * S + sb + 2 * cp);
  const int col = tid & 63;        // reduce-phase column
  const int rb  = tid >> 6;        // reduce-phase row base (rows rb+4j)
  const float bcv = bcell[lane * S + sb + col];
  const float wov = Wout[sb + col];
  for (int idx = tid; idx < 2 * S; idx += NT)
    wg_lds[idx] = (lane > 0) ? Wcomb[(size_t)(lane - 1) * 2 * S + idx] : 0.0f;
  const float bg = (lane > 0) ? bcomb[lane - 1] : 0.0f;
  // stage/gate mapping: 32 threads per row, 8 rows per pass, 2 passes
  const int grow = tid >> 5, gch = tid & 31;
  __syncthreads();

  float oacc[4] = {0.f, 0.f, 0.f, 0.f};

  for (int t = 0; t < T; ++t) {
    // ---- phase A: x stage (16 rows, 2 writes/thread) + split-phase polls --
    h_lds[grow * HS2 + gch] =
        x[(((size_t)lane * BATCH + r0 + grow) * T + t) * FIN + gch];
    h_lds[(grow + 8) * HS2 + gch] =
        x[(((size_t)lane * BATCH + r0 + grow + 8) * T + t) * FIN + gch];
    if (tid == 0) {
      if (t > 0)                  while (ld_cnt(cnt_own)  < 8u * (unsigned)t) {}
      if (lane > 0)               while (ld_cnt(cnt_prod) < 8u * (unsigned)(t + 1)) {}
      if (lane < 3 && t >= DEPTH) while (ld_cnt(cnt_cons) < 8u * (unsigned)(t - 3)) {}
    }
    __syncthreads();

    // ---- phase B: coherent ring loads + wave-local gate + stage hc --------
    #pragma unroll
    for (int pass = 0; pass < 2; ++pass) {
      const int row = pass * 8 + grow;
      float4 hv[4], pv[4];
      const float* hb = ring + ((size_t)(lane * DEPTH + ((t - 1) & 3)) * BATCH + r0 + row) * S + gch * 4;
      const float* pb = ring + ((size_t)((lane - 1) * DEPTH + (t & 3)) * BATCH + r0 + row) * S + gch * 4;
      if (t > 0) {
        if (lane > 0) cload_row2(hv, pv, hb, pb);
        else          cload_row(hv, hb);
      } else {
        #pragma unroll
        for (int j = 0; j < 4; ++j) hv[j] = make_float4(0.f, 0.f, 0.f, 0.f);
        if (lane > 0) cload_row(pv, pb);
      }
      if (lane > 0) {
        float gs = 0.0f;
        #pragma unroll
        for (int j = 0; j < 4; ++j) {
          const float* wh = &wg_lds[j * 128 + gch * 4];
          const float* wp = wh + S;
          gs += hv[j].x * wh[0] + hv[j].y * wh[1] + hv[j].z * wh[2] + hv[j].w * wh[3];
          gs += pv[j].x * wp[0] + pv[j].y * wp[1] + pv[j].z * wp[2] + pv[j].w * wp[3];
        }
        gs += __shfl_xor(gs, 1);  gs += __shfl_xor(gs, 2);  gs += __shfl_xor(gs, 4);
        gs += __shfl_xor(gs, 8);  gs += __shfl_xor(gs, 16);  // 32-lane row halves
        const float w = 1.0f / (1.0f + __expf(-(gs + bg)));
        #pragma unroll
        for (int j = 0; j < 4; ++j) {  // hc = p + w*(h-p)
          hv[j].x = fmaf(w, hv[j].x - pv[j].x, pv[j].x);
          hv[j].y = fmaf(w, hv[j].y - pv[j].y, pv[j].y);
          hv[j].z = fmaf(w, hv[j].z - pv[j].z, pv[j].z);
          hv[j].w = fmaf(w, hv[j].w - pv[j].w, pv[j].w);
        }
      }
      #pragma unroll
      for (int j = 0; j < 4; ++j)
        *(float4*)&h_lds[row * HS2 + 32 + j * 128 + gch * 4] = hv[j];
    }
    __syncthreads();

    // ---- phase C: matvec, 16 rows, 2 cols/thread (8 FMA per broadcast) ----
    #pragma unroll
    for (int r = 0; r < RPG; ++r) {
      const float* hrow = &h_lds[r * HS2 + kc * KPW];  // 272B-aligned
      float2 a0 = {0.f, 0.f}, a1 = {0.f, 0.f}, a2 = {0.f, 0.f}, a3 = {0.f, 0.f};
      #pragma unroll
      for (int u = 0; u < 17; ++u) {
        const float4 h4 = *(const float4*)(hrow + u * 4);  // 2 addrs/wave: free
        a0 = fma2v(h4.x, U2[u * 4 + 0], a0);
        a1 = fma2v(h4.y, U2[u * 4 + 1], a1);
        a2 = fma2v(h4.z, U2[u * 4 + 2], a2);
        a3 = fma2v(h4.w, U2[u * 4 + 3], a3);
      }
      float2 s2;
      s2.x = (a0.x + a1.x) + (a2.x + a3.x);
      s2.y = (a0.y + a1.y) + (a2.y + a3.y);
      *(float2*)&red[(kc * RPG + r) * RS2 + 2 * cp] = s2;
    }
    __syncthreads();

    // ---- phase D: reduce 8 kc + tanh + coherent store (4 rows/thread) -----
    float* slot = ring + ((size_t)(lane * DEPTH + (t & 3)) * BATCH + r0) * S + sb;
    #pragma unroll
    for (int j = 0; j < 4; ++j) {
      const int r = rb + 4 * j;
      float s2 = bcv;
      #pragma unroll
      for (int c = 0; c < 8; ++c) s2 += red[(c * RPG + r) * RS2 + col];
      const float aa = fabsf(s2), ee = __expf(2.0f * aa);
      const float th = copysignf(1.0f - 2.0f / (ee + 1.0f), s2);
      cstore1(slot + (size_t)r * S + col, th);
      if (t == T - 1) oacc[j] = th * wov;
    }
    __syncthreads();  // drains vmcnt -> cstores at MALL before arrive
    if (tid == 0)
      __hip_atomic_fetch_add(cnt_own, 1u, __ATOMIC_RELAXED, __HIP_MEMORY_SCOPE_AGENT);
  }

  // ---- output: out[lane*256 + r] = h_T[r] . Wout --------------------------
  #pragma unroll
  for (int j = 0; j < 4; ++j) {
    float v = oacc[j];
    #pragma unroll
    for (int m = 1; m < 64; m <<= 1) v += __shfl_xor(v, m);
    if ((tid & 63) == 0) obuf[rb + 4 * j] = v;
  }
  __syncthreads();
  if (tid < 16)
    cstore1(ws + OUTP_OFF + (size_t)((gid * 8 + sl) * 16 + tid), obuf[tid]);
  __syncthreads();
  if (tid == 0)
    __hip_atomic_fetch_add(cnt_own, 1u, __ATOMIC_RELAXED, __HIP_MEMORY_SCOPE_AGENT);
  if (sl == 0) {
    if (tid == 0)
      while (ld_cnt(cnt_own) < 8u * (unsigned)(T + 1)) {}
    __syncthreads();
    if (tid < 128) {
      const int sli = tid >> 4, r = tid & 15;
      red[tid] = cload1(ws + OUTP_OFF + (size_t)((gid * 8 + sli) * 16 + r));
    }
    __syncthreads();
    if (tid < 16) {
      float s2 = 0.f;
      #pragma unroll
      for (int sli = 0; sli < 8; ++sli) s2 += red[sli * 16 + tid];
      out[lane * BATCH + r0 + tid] = s2;
    }
  }
}

extern "C" void kernel_launch(void* const* d_in, const int* in_sizes, int n_in,
                              void* d_out, int out_size, void* d_ws, size_t ws_size,
                              hipStream_t stream) {
  (void)in_sizes; (void)n_in; (void)out_size; (void)ws_size;
  rnn_pipe5<<<dim3(NWG), dim3(NT), 0, stream>>>(
      (const float*)d_in[0],   // inputs
      (const float*)d_in[1],   // W_cell
      (const float*)d_in[2],   // b_cell
      (const float*)d_in[3],   // W_comb
      (const float*)d_in[4],   // b_comb
      (const float*)d_in[5],   // W_out
      (float*)d_out,
      (float*)d_ws);
}

// Round 9
// 478.682 us; speedup vs baseline: 2.4632x; 1.5914x over previous
//
#include <hip/hip_runtime.h>
#include <math.h>

// Problem constants
#define NSEQ 4
#define BATCH 256
#define T 64
#define FIN 32
#define S 512
#define KTOT 544     // FIN + S unified k-dimension

// Pipelined decomposition: 4 lanes concurrent (lane i lags i-1 by 1 step).
// Per lane: 16 groups x 16 rows, 8 slice-WGs x 64 cols. 4*16*8 = 512 WGs.
// NT=256 (4 waves), 2 WG/CU. Matvec = MFMA: wave -> 16x16 col-tile, 17
// K-tiles of mfma_f32_16x16x32_bf16, SPLIT-BF16 (hi+lo residual, 3 products)
// for fp32-grade accuracy. No red[] LDS, no reduce phase: MFMA acc holds
// the complete sums.
#define NT 256
#define NWG 512
#define RPG 16
#define SW 64
#define DEPTH 4
#define NKT 17       // K-tiles of 32 (544/32)

// ws float offsets
#define RING_SZ  (4ull * DEPTH * BATCH * S)        // 8 MB state ring
#define OUTP_OFF RING_SZ                            // [gid][sl][16] partials
#define CTL_OFF  (RING_SZ + 16384ull)               // counters: gid*32 uints

#define FLAG_MAGIC 0x13572468u

#define AS 552   // A-LDS row stride in bf16 elems (544 + 8 pad)

typedef __attribute__((ext_vector_type(8))) short short8;  // 8 bf16 (4 VGPRs)
typedef __attribute__((ext_vector_type(4))) float f32x4;   // MFMA C/D

// ---- split-bf16: value = hi (truncated bf16) + lo (bf16 of residual) ------
__device__ __forceinline__ unsigned short bf_hi(float f) {
  return (unsigned short)(__float_as_uint(f) >> 16);
}
__device__ __forceinline__ float bf_hi_f(float f) {
  return __uint_as_float(__float_as_uint(f) & 0xFFFF0000u);
}

__device__ __forceinline__ unsigned ld_cnt(const unsigned* p) {
  return __hip_atomic_load(p, __ATOMIC_RELAXED, __HIP_MEMORY_SCOPE_AGENT);
}

// ---- coherent (MALL) ring I/O via sc0 sc1 asm (R4-proven) -----------------
__device__ __forceinline__ void cstore1(float* p, float v) {
  asm volatile("global_store_dword %0, %1, off sc0 sc1" :: "v"(p), "v"(v) : "memory");
}
__device__ __forceinline__ float cload1(const float* p) {
  float v;
  asm volatile("global_load_dword %0, %1, off sc0 sc1\n\ts_waitcnt vmcnt(0)"
               : "=v"(v) : "v"(p) : "memory");
  return v;
}
__device__ __forceinline__ void cload_row(float4* d, const float* p) {
  asm volatile(
      "global_load_dwordx4 %0, %4, off sc0 sc1\n\t"
      "global_load_dwordx4 %1, %4, off offset:512 sc0 sc1\n\t"
      "global_load_dwordx4 %2, %4, off offset:1024 sc0 sc1\n\t"
      "global_load_dwordx4 %3, %4, off offset:1536 sc0 sc1\n\t"
      "s_waitcnt vmcnt(0)"
      : "=&v"(d[0]), "=&v"(d[1]), "=&v"(d[2]), "=&v"(d[3])
      : "v"(p) : "memory");
}
__device__ __forceinline__ void cload_row2(float4* h, float4* q,
                                           const float* ph, const float* pp) {
  asm volatile(
      "global_load_dwordx4 %0, %8, off sc0 sc1\n\t"
      "global_load_dwordx4 %1, %8, off offset:512 sc0 sc1\n\t"
      "global_load_dwordx4 %2, %8, off offset:1024 sc0 sc1\n\t"
      "global_load_dwordx4 %3, %8, off offset:1536 sc0 sc1\n\t"
      "global_load_dwordx4 %4, %9, off sc0 sc1\n\t"
      "global_load_dwordx4 %5, %9, off offset:512 sc0 sc1\n\t"
      "global_load_dwordx4 %6, %9, off offset:1024 sc0 sc1\n\t"
      "global_load_dwordx4 %7, %9, off offset:1536 sc0 sc1\n\t"
      "s_waitcnt vmcnt(0)"
      : "=&v"(h[0]), "=&v"(h[1]), "=&v"(h[2]), "=&v"(h[3]),
        "=&v"(q[0]), "=&v"(q[1]), "=&v"(q[2]), "=&v"(q[3])
      : "v"(ph), "v"(pp) : "memory");
}

extern "C" __global__ void __launch_bounds__(NT, 1)
rnn_mfma(const float* __restrict__ x,      // [4][256][64][32]
         const float* __restrict__ Wcell,  // [4][544][512]
         const float* __restrict__ bcell,  // [4][512]
         const float* __restrict__ Wcomb,  // [3][1024]
         const float* __restrict__ bcomb,  // [3]
         const float* __restrict__ Wout,   // [512]
         float* __restrict__ out,          // [1024] = [lane][batch]
         float* __restrict__ ws)
{
  const int b    = blockIdx.x;
  const int sl   = b & 7;          // slice (round-robins XCDs)
  const int gid  = b >> 3;         // 0..63 = lane*16 + grp
  const int lane = gid >> 4;       // RNN lane
  const int grp  = gid & 15;
  const int r0 = grp * RPG, sb = sl * SW;
  const int tid = threadIdx.x;

  __shared__ __align__(16) unsigned short A1[RPG * AS];  // 17.3 KB hi [x|hc]
  __shared__ __align__(16) unsigned short A2[RPG * AS];  // 17.3 KB lo
  __shared__ float wg_lds[2 * S];                        //  4.0 KB gate weights
  __shared__ float obuf[64];
  __shared__ float fbuf[128];

  float* ring = ws;
  unsigned* ctl      = (unsigned*)(ws + CTL_OFF);
  unsigned* cnt_own  = ctl + gid * 32;
  unsigned* flg_own  = cnt_own + 16;
  unsigned* cnt_prod = ctl + (gid - 16) * 32;  // valid iff lane>0
  unsigned* cnt_cons = ctl + (gid + 16) * 32;  // valid iff lane<3

  // ---- init handshake (poison-keyed flag) ----
  if (sl == 0 && tid == 0) {
    __hip_atomic_store(cnt_own, 0u, __ATOMIC_RELAXED, __HIP_MEMORY_SCOPE_AGENT);
    __hip_atomic_store(flg_own, FLAG_MAGIC, __ATOMIC_RELEASE, __HIP_MEMORY_SCOPE_AGENT);
  }
  if (tid == 0) {
    while (__hip_atomic_load(flg_own, __ATOMIC_ACQUIRE, __HIP_MEMORY_SCOPE_AGENT) != FLAG_MAGIC)
      __builtin_amdgcn_s_sleep(1);
    if (lane > 0)
      while (__hip_atomic_load(cnt_prod + 16, __ATOMIC_ACQUIRE, __HIP_MEMORY_SCOPE_AGENT) != FLAG_MAGIC)
        __builtin_amdgcn_s_sleep(1);
    if (lane < 3)
      while (__hip_atomic_load(cnt_cons + 16, __ATOMIC_ACQUIRE, __HIP_MEMORY_SCOPE_AGENT) != FLAG_MAGIC)
        __builtin_amdgcn_s_sleep(1);
  }

  // ---- per-thread constants ----
  const float* Wc = Wcell + (size_t)lane * KTOT * S;
  // MFMA mapping: wave wt owns cols [sb+wt*16, +16); within wave:
  //   A-frag: row m = wl&15, k = q*8+j   (q = wl>>4)
  //   B-frag: col n = wl&15, k = q*8+j
  //   C/D:    col  = wl&15, row = q*4+reg
  const int wl = tid & 63, wt = tid >> 6;
  const int bn = wl & 15, q = wl >> 4;
  const int ncol = sb + wt * 16 + bn;
  short8 B1[NKT], B2[NKT];   // split-bf16 weight frags: 136 regs, static
  #pragma unroll
  for (int kt = 0; kt < NKT; ++kt) {
    short8 b1, b2;
    #pragma unroll
    for (int j = 0; j < 8; ++j) {
      const float w = Wc[(size_t)(kt * 32 + q * 8 + j) * S + ncol];
      b1[j] = (short)bf_hi(w);
      b2[j] = (short)bf_hi(w - bf_hi_f(w));
    }
    B1[kt] = b1; B2[kt] = b2;
  }
  const float bcv = bcell[lane * S + ncol];
  const float wov = Wout[ncol];
  for (int idx = tid; idx < 2 * S; idx += NT)
    wg_lds[idx] = (lane > 0) ? Wcomb[(size_t)(lane - 1) * 2 * S + idx] : 0.0f;
  const float bg = (lane > 0) ? bcomb[lane - 1] : 0.0f;
  // stage/gate mapping: 32 threads per row, 8 rows per pass, 2 passes
  const int grow = tid >> 5, gch = tid & 31;
  __syncthreads();

  float oacc[4] = {0.f, 0.f, 0.f, 0.f};

  for (int t = 0; t < T; ++t) {
    // ---- phase A: x stage (split-bf16 into A rows k<32) + polls ----
    {
      const float f0 = x[(((size_t)lane * BATCH + r0 + grow) * T + t) * FIN + gch];
      const float f1 = x[(((size_t)lane * BATCH + r0 + grow + 8) * T + t) * FIN + gch];
      A1[grow * AS + gch]       = bf_hi(f0);
      A2[grow * AS + gch]       = bf_hi(f0 - bf_hi_f(f0));
      A1[(grow + 8) * AS + gch] = bf_hi(f1);
      A2[(grow + 8) * AS + gch] = bf_hi(f1 - bf_hi_f(f1));
    }
    if (tid == 0) {
      if (t > 0)                  while (ld_cnt(cnt_own)  < 8u * (unsigned)t) {}
      if (lane > 0)               while (ld_cnt(cnt_prod) < 8u * (unsigned)(t + 1)) {}
      if (lane < 3 && t >= DEPTH) while (ld_cnt(cnt_cons) < 8u * (unsigned)(t - 3)) {}
    }
    __syncthreads();

    // ---- phase B: ring loads + wave-local gate (fp32) + split-stage hc ----
    #pragma unroll
    for (int pass = 0; pass < 2; ++pass) {
      const int row = pass * 8 + grow;
      float4 hv[4], pv[4];
      const float* hb = ring + ((size_t)(lane * DEPTH + ((t - 1) & 3)) * BATCH + r0 + row) * S + gch * 4;
      const float* pb = ring + ((size_t)((lane - 1) * DEPTH + (t & 3)) * BATCH + r0 + row) * S + gch * 4;
      if (t > 0) {
        if (lane > 0) cload_row2(hv, pv, hb, pb);
        else          cload_row(hv, hb);
      } else {
        #pragma unroll
        for (int j = 0; j < 4; ++j) hv[j] = make_float4(0.f, 0.f, 0.f, 0.f);
        if (lane > 0) cload_row(pv, pb);
      }
      if (lane > 0) {
        float gs = 0.0f;
        #pragma unroll
        for (int j = 0; j < 4; ++j) {
          const float* wh = &wg_lds[j * 128 + gch * 4];
          const float* wp = wh + S;
          gs += hv[j].x * wh[0] + hv[j].y * wh[1] + hv[j].z * wh[2] + hv[j].w * wh[3];
          gs += pv[j].x * wp[0] + pv[j].y * wp[1] + pv[j].z * wp[2] + pv[j].w * wp[3];
        }
        gs += __shfl_xor(gs, 1);  gs += __shfl_xor(gs, 2);  gs += __shfl_xor(gs, 4);
        gs += __shfl_xor(gs, 8);  gs += __shfl_xor(gs, 16);  // 32-lane row halves
        const float w = 1.0f / (1.0f + __expf(-(gs + bg)));
        #pragma unroll
        for (int j = 0; j < 4; ++j) {  // hc = p + w*(h-p)
          hv[j].x = fmaf(w, hv[j].x - pv[j].x, pv[j].x);
          hv[j].y = fmaf(w, hv[j].y - pv[j].y, pv[j].y);
          hv[j].z = fmaf(w, hv[j].z - pv[j].z, pv[j].z);
          hv[j].w = fmaf(w, hv[j].w - pv[j].w, pv[j].w);
        }
      }
      #pragma unroll
      for (int j = 0; j < 4; ++j) {
        ushort4 h4, l4;
        h4.x = bf_hi(hv[j].x); l4.x = bf_hi(hv[j].x - bf_hi_f(hv[j].x));
        h4.y = bf_hi(hv[j].y); l4.y = bf_hi(hv[j].y - bf_hi_f(hv[j].y));
        h4.z = bf_hi(hv[j].z); l4.z = bf_hi(hv[j].z - bf_hi_f(hv[j].z));
        h4.w = bf_hi(hv[j].w); l4.w = bf_hi(hv[j].w - bf_hi_f(hv[j].w));
        const int ai = row * AS + 32 + j * 128 + gch * 4;
        *(ushort4*)&A1[ai] = h4;
        *(ushort4*)&A2[ai] = l4;
      }
    }
    __syncthreads();

    // ---- phase C: MFMA 16x16 tile, 17 K-tiles x 3 split products ----------
    f32x4 acc = {0.f, 0.f, 0.f, 0.f};
    {
      const unsigned short* ar1 = &A1[bn * AS + q * 8];
      const unsigned short* ar2 = &A2[bn * AS + q * 8];
      #pragma unroll
      for (int kt = 0; kt < NKT; ++kt) {
        const short8 a1 = *(const short8*)(ar1 + kt * 32);
        const short8 a2 = *(const short8*)(ar2 + kt * 32);
        acc = __builtin_amdgcn_mfma_f32_16x16x32_bf16(a1, B1[kt], acc, 0, 0, 0);
        acc = __builtin_amdgcn_mfma_f32_16x16x32_bf16(a1, B2[kt], acc, 0, 0, 0);
        acc = __builtin_amdgcn_mfma_f32_16x16x32_bf16(a2, B1[kt], acc, 0, 0, 0);
      }
    }

    // ---- epilogue: +bias, tanh, coherent ring store (D-layout direct) -----
    float* slot = ring + ((size_t)(lane * DEPTH + (t & 3)) * BATCH + r0) * S + sb;
    #pragma unroll
    for (int reg = 0; reg < 4; ++reg) {
      const float s2 = acc[reg] + bcv;
      const float aa = fabsf(s2), ee = __expf(2.0f * aa);
      const float tv = copysignf(1.0f - 2.0f / (ee + 1.0f), s2);
      cstore1(slot + (size_t)(q * 4 + reg) * S + wt * 16 + bn, tv);
      if (t == T - 1) oacc[reg] = tv * wov;
    }
    asm volatile("s_waitcnt vmcnt(0)" ::: "memory");  // own cstores at MALL
    __syncthreads();  // all threads drained -> safe to arrive + reuse A-LDS
    if (tid == 0)
      __hip_atomic_fetch_add(cnt_own, 1u, __ATOMIC_RELAXED, __HIP_MEMORY_SCOPE_AGENT);
  }

  // ---- output: out[lane*256 + r] = h_T[r] . Wout --------------------------
  #pragma unroll
  for (int reg = 0; reg < 4; ++reg) {
    float v = oacc[reg];
    v += __shfl_xor(v, 1); v += __shfl_xor(v, 2);
    v += __shfl_xor(v, 4); v += __shfl_xor(v, 8);  // sum 16 cols of the tile
    if (bn == 0) obuf[wt * 16 + q * 4 + reg] = v;
  }
  __syncthreads();
  if (tid < 16) {
    const float v = obuf[tid] + obuf[16 + tid] + obuf[32 + tid] + obuf[48 + tid];
    cstore1(ws + OUTP_OFF + (size_t)((gid * 8 + sl) * 16 + tid), v);
  }
  asm volatile("s_waitcnt vmcnt(0)" ::: "memory");
  __syncthreads();
  if (tid == 0)
    __hip_atomic_fetch_add(cnt_own, 1u, __ATOMIC_RELAXED, __HIP_MEMORY_SCOPE_AGENT);
  if (sl == 0) {
    if (tid == 0)
      while (ld_cnt(cnt_own) < 8u * (unsigned)(T + 1)) {}
    __syncthreads();
    if (tid < 128) {
      const int sli = tid >> 4, r = tid & 15;
      fbuf[tid] = cload1(ws + OUTP_OFF + (size_t)((gid * 8 + sli) * 16 + r));
    }
    __syncthreads();
    if (tid < 16) {
      float s2 = 0.f;
      #pragma unroll
      for (int sli = 0; sli < 8; ++sli) s2 += fbuf[sli * 16 + tid];
      out[lane * BATCH + r0 + tid] = s2;
    }
  }
}

extern "C" void kernel_launch(void* const* d_in, const int* in_sizes, int n_in,
                              void* d_out, int out_size, void* d_ws, size_t ws_size,
                              hipStream_t stream) {
  (void)in_sizes; (void)n_in; (void)out_size; (void)ws_size;
  rnn_mfma<<<dim3(NWG), dim3(NT), 0, stream>>>(
      (const float*)d_in[0],   // inputs
      (const float*)d_in[1],   // W_cell
      (const float*)d_in[2],   // b_cell
      (const float*)d_in[3],   // W_comb
      (const float*)d_in[4],   // b_comb
      (const float*)d_in[5],   // W_out
      (float*)d_out,
      (float*)d_ws);
}